// Round 4
// baseline (161.222 us; speedup 1.0000x reference)
//
#include <hip/hip_runtime.h>
#include <math.h>

#define NO 10
#define NFEAT 68

// Feature f -> (orbital row oi, orbital col oj, factor)
__device__ const int g_oi[NFEAT] = {
    0,0,0,0,0,0,0,0,0,0,
    1,1,1,1,1,1,1,1,1,
    2,2,2,3,3,3,4,4,4,
    2,2,2,2,2,3,3,3,3,3,4,4,4,4,4,
    5,5,5,5,5,6,6,6,6,6,7,7,7,7,7,8,8,8,8,8,9,9,9,9,9
};
__device__ const int g_oj[NFEAT] = {
    0,1,2,3,4,5,6,7,8,9,
    1,2,3,4,5,6,7,8,9,
    2,3,4,2,3,4,2,3,4,
    5,6,7,8,9,5,6,7,8,9,5,6,7,8,9,
    5,6,7,8,9,5,6,7,8,9,5,6,7,8,9,5,6,7,8,9,5,6,7,8,9
};
__device__ const float g_fac[NFEAT] = {
    0.5f,1,1,1,1,1,1,1,1,1,
    0.5f,1,1,1,1,1,1,1,1,
    0.5f,0.5f,0.5f,0.5f,0.5f,0.5f,0.5f,0.5f,0.5f,
    1,1,1,1,1,1,1,1,1,1,1,1,1,1,1,
    0.5f,0.5f,0.5f,0.5f,0.5f,0.5f,0.5f,0.5f,0.5f,0.5f,
    0.5f,0.5f,0.5f,0.5f,0.5f,0.5f,0.5f,0.5f,0.5f,0.5f,
    0.5f,0.5f,0.5f,0.5f,0.5f
};

// Grid-stride float4 zero fill, exact bounds.
__global__ void zero_kernel(float* __restrict__ out, size_t n_floats) {
    size_t n4 = n_floats >> 2;
    float4* o4 = (float4*)out;
    float4 z = make_float4(0.f, 0.f, 0.f, 0.f);
    size_t stride = (size_t)gridDim.x * blockDim.x;
    for (size_t i = (size_t)blockIdx.x * blockDim.x + threadIdx.x; i < n4; i += stride)
        o4[i] = z;
    size_t tid = (size_t)blockIdx.x * blockDim.x + threadIdx.x;
    size_t tail = n4 << 2;
    if (tid < (n_floats - tail)) out[tail + tid] = 0.f;
}

__device__ __forceinline__ void safe_add(float* out, size_t idx, size_t lim, float v) {
    if (idx < lim) atomicAdd(out + idx, v);
}

// ---------------- REAL-ONLY layout: out[d][k][r][c], float, real part of H ----------------
// Out = S + S^T; S = diag blocks + sum_e sin(2pi k.R)*(-v_d)*fac*feat at (i,j) block.

__global__ void diag_real(const float* __restrict__ nf, float* __restrict__ out,
                          int N, int NK, size_t lim) {
    int w = blockIdx.x * blockDim.x + threadIdx.x;
    if (w >= N * NFEAT) return;
    int a = w / NFEAT;
    int f = w - a * NFEAT;
    float val = g_fac[f] * nf[w];
    int oi = g_oi[f], oj = g_oj[f];
    int NR = N * NO;
    size_t perk = (size_t)NR * NR;
    size_t p1 = (size_t)(a * NO + oi) * NR + (a * NO + oj);
    size_t p2 = (size_t)(a * NO + oj) * NR + (a * NO + oi);
    for (int dk = 0; dk < 3 * NK; ++dk) {
        size_t b = (size_t)dk * perk;
        safe_add(out, b + p1, lim, val);
        safe_add(out, b + p2, lim, val);
    }
}

__global__ void edge_real(const float* __restrict__ ef, const float* __restrict__ ev,
                          const float* __restrict__ ecs, const float* __restrict__ kp,
                          const int* __restrict__ eidx, float* __restrict__ out,
                          int E, int N, int NK, size_t lim) {
    int w = blockIdx.x * blockDim.x + threadIdx.x;
    if (w >= E * NFEAT) return;
    int e = w / NFEAT;
    int f = w - e * NFEAT;

    int i = eidx[e];
    int j = eidx[E + e];
    float vd[3];
    vd[0] = ev[e * 3 + 0]; vd[1] = ev[e * 3 + 1]; vd[2] = ev[e * 3 + 2];
    float r0 = ecs[e * 3 + 0], r1 = ecs[e * 3 + 1], r2 = ecs[e * 3 + 2];
    float val = g_fac[f] * ef[w];
    int oi = g_oi[f], oj = g_oj[f];

    int NR = N * NO;
    size_t perk = (size_t)NR * NR;
    size_t off_f = (size_t)(i * NO + oi) * NR + (j * NO + oj);
    size_t off_t = (size_t)(j * NO + oj) * NR + (i * NO + oi);

    const float TWO_PI = 6.283185307179586f;
    for (int k = 0; k < NK; ++k) {
        float th = TWO_PI * (kp[k * 3 + 0] * r0 + kp[k * 3 + 1] * r1 + kp[k * 3 + 2] * r2);
        float s = __sinf(th) * val;  // Re(1j*phase) = sin(th)
        // use precise sinf to be safe on accuracy:
        s = sinf(th) * val;
#pragma unroll 3
        for (int d = 0; d < 3; ++d) {
            float re = -vd[d] * s;
            size_t b = ((size_t)d * NK + k) * perk;
            safe_add(out, b + off_f, lim, re);
            safe_add(out, b + off_t, lim, re);
        }
    }
}

// ---------------- COMPLEX interleaved layout (fallback hypothesis) ----------------

__global__ void diag_cplx(const float* __restrict__ nf, float* __restrict__ out,
                          int N, int NK, size_t lim) {
    int w = blockIdx.x * blockDim.x + threadIdx.x;
    if (w >= N * NFEAT) return;
    int a = w / NFEAT;
    int f = w - a * NFEAT;
    float val = g_fac[f] * nf[w];
    int oi = g_oi[f], oj = g_oj[f];
    int NR = N * NO;
    size_t perk = (size_t)NR * NR * 2;
    size_t p1 = ((size_t)(a * NO + oi) * NR + (a * NO + oj)) * 2;
    size_t p2 = ((size_t)(a * NO + oj) * NR + (a * NO + oi)) * 2;
    for (int dk = 0; dk < 3 * NK; ++dk) {
        size_t b = (size_t)dk * perk;
        safe_add(out, b + p1, lim, val);
        safe_add(out, b + p2, lim, val);
    }
}

__global__ void edge_cplx(const float* __restrict__ ef, const float* __restrict__ ev,
                          const float* __restrict__ ecs, const float* __restrict__ kp,
                          const int* __restrict__ eidx, float* __restrict__ out,
                          int E, int N, int NK, size_t lim) {
    int w = blockIdx.x * blockDim.x + threadIdx.x;
    if (w >= E * NFEAT) return;
    int e = w / NFEAT;
    int f = w - e * NFEAT;

    int i = eidx[e];
    int j = eidx[E + e];
    float vd[3];
    vd[0] = ev[e * 3 + 0]; vd[1] = ev[e * 3 + 1]; vd[2] = ev[e * 3 + 2];
    float r0 = ecs[e * 3 + 0], r1 = ecs[e * 3 + 1], r2 = ecs[e * 3 + 2];
    float val = g_fac[f] * ef[w];
    int oi = g_oi[f], oj = g_oj[f];

    int NR = N * NO;
    size_t perk = (size_t)NR * NR * 2;
    size_t off_f = ((size_t)(i * NO + oi) * NR + (j * NO + oj)) * 2;
    size_t off_h = ((size_t)(j * NO + oj) * NR + (i * NO + oi)) * 2;

    const float TWO_PI = 6.283185307179586f;
    for (int k = 0; k < NK; ++k) {
        float th = TWO_PI * (kp[k * 3 + 0] * r0 + kp[k * 3 + 1] * r1 + kp[k * 3 + 2] * r2);
        float s, c;
        sincosf(th, &s, &c);
        float sv = s * val, cv = c * val;
#pragma unroll 3
        for (int d = 0; d < 3; ++d) {
            float a = -vd[d];
            float re = a * sv, im = a * cv;
            size_t b = ((size_t)d * NK + k) * perk;
            safe_add(out, b + off_f,     lim, re);
            safe_add(out, b + off_f + 1, lim, im);
            safe_add(out, b + off_h,     lim, re);
            safe_add(out, b + off_h + 1, lim, -im);
        }
    }
}

extern "C" void kernel_launch(void* const* d_in, const int* in_sizes, int n_in,
                              void* d_out, int out_size, void* d_ws, size_t ws_size,
                              hipStream_t stream) {
    const float* ef  = (const float*)d_in[0];   // edge_features   [E,68]
    const float* nf  = (const float*)d_in[1];   // node_features   [N,68]
    const float* ev  = (const float*)d_in[2];   // edge_vectors    [E,3]
    const float* ecs = (const float*)d_in[3];   // edge_cell_shift [E,3]
    const float* kp  = (const float*)d_in[4];   // kpoints         [NK,3]
    const int*  eidx = (const int*)d_in[5];     // edge_index      [2,E]
    float* out = (float*)d_out;

    int E  = in_sizes[0] / NFEAT;
    int N  = in_sizes[1] / NFEAT;
    int NK = in_sizes[4] / 3;
    int NR = N * NO;

    size_t nreal = (size_t)3 * NK * NR * NR;   // real-part-only float count
    size_t lim = (size_t)out_size;             // NEVER write past out_size floats

    zero_kernel<<<2048, 256, 0, stream>>>(out, lim);

    int workN = N * NFEAT;
    int workE = E * NFEAT;
    bool cplx = ((size_t)out_size >= 2 * nreal);

    if (cplx) {
        diag_cplx<<<(workN + 255) / 256, 256, 0, stream>>>(nf, out, N, NK, lim);
        edge_cplx<<<(workE + 255) / 256, 256, 0, stream>>>(ef, ev, ecs, kp, eidx, out, E, N, NK, lim);
    } else {
        diag_real<<<(workN + 255) / 256, 256, 0, stream>>>(nf, out, N, NK, lim);
        edge_real<<<(workE + 255) / 256, 256, 0, stream>>>(ef, ev, ecs, kp, eidx, out, E, N, NK, lim);
    }
}

// Round 5
// 99.719 us; speedup vs baseline: 1.6168x; 1.6168x over previous
//
#include <hip/hip_runtime.h>
#include <math.h>

#define NO 10
#define NFEAT 68
#define MAXNR 2048          // max N*NO supported (N=200 -> 2000)
#define MAXLIST 1024        // max incident-edge entries per atom (avg ~60)
#define HR 5                // orbital rows per workgroup (NO/2)

// Feature f -> (orbital row oi, orbital col oj, factor)
__device__ const int g_oi[NFEAT] = {
    0,0,0,0,0,0,0,0,0,0,
    1,1,1,1,1,1,1,1,1,
    2,2,2,3,3,3,4,4,4,
    2,2,2,2,2,3,3,3,3,3,4,4,4,4,4,
    5,5,5,5,5,6,6,6,6,6,7,7,7,7,7,8,8,8,8,8,9,9,9,9,9
};
__device__ const int g_oj[NFEAT] = {
    0,1,2,3,4,5,6,7,8,9,
    1,2,3,4,5,6,7,8,9,
    2,3,4,2,3,4,2,3,4,
    5,6,7,8,9,5,6,7,8,9,5,6,7,8,9,
    5,6,7,8,9,5,6,7,8,9,5,6,7,8,9,5,6,7,8,9,5,6,7,8,9
};
__device__ const float g_fac[NFEAT] = {
    0.5f,1,1,1,1,1,1,1,1,1,
    0.5f,1,1,1,1,1,1,1,1,
    0.5f,0.5f,0.5f,0.5f,0.5f,0.5f,0.5f,0.5f,0.5f,
    1,1,1,1,1,1,1,1,1,1,1,1,1,1,1,
    0.5f,0.5f,0.5f,0.5f,0.5f,0.5f,0.5f,0.5f,0.5f,0.5f,
    0.5f,0.5f,0.5f,0.5f,0.5f,0.5f,0.5f,0.5f,0.5f,0.5f,
    0.5f,0.5f,0.5f,0.5f,0.5f
};

// Owner-computes: workgroup (i, k, h) produces output rows [i*NO + h*HR, +HR)
// over all NR columns, for all 3 directions. Every output float written once.
// out[d][k][r][c] = S[r][c] + S[c][r] (real part), where
//   S = diag(onsite blocks) + sum_e sin(2pi k.R_e) * (-v_d) * fac * feat at block (src,dst).
__global__ __launch_bounds__(512)
void fused_kernel(const float* __restrict__ ef, const float* __restrict__ nf,
                  const float* __restrict__ ev, const float* __restrict__ ecs,
                  const float* __restrict__ kp, const int* __restrict__ eidx,
                  float* __restrict__ out,
                  int E, int N, int NK, size_t lim) {
    __shared__ float acc[HR * MAXNR];     // 40 KB accumulator (5 rows x NR cols)
    __shared__ float sins[MAXLIST];       // sin(2pi k.R) per incident entry
    __shared__ int   elist[MAXLIST];      // entry = e*2 + dir (dir 0: i==src, 1: i==dst)
    __shared__ int   mcnt;

    const int i   = blockIdx.x;
    const int k   = blockIdx.y;
    const int r0  = blockIdx.z * HR;      // first orbital row owned
    const int tid = threadIdx.x;
    const int nthr = blockDim.x;
    const int NR  = N * NO;
    if (NR > MAXNR) return;

    if (tid == 0) mcnt = 0;
    __syncthreads();

    // Scan edge headers for edges incident to atom i (either endpoint).
    for (int e = tid; e < E; e += nthr) {
        int s = eidx[e], t = eidx[E + e];
        if (s == i) { int p = atomicAdd(&mcnt, 1); if (p < MAXLIST) elist[p] = e * 2; }
        if (t == i) { int p = atomicAdd(&mcnt, 1); if (p < MAXLIST) elist[p] = e * 2 + 1; }
    }
    __syncthreads();
    const int m = min(mcnt, MAXLIST);

    // Per-entry sin(2pi k . R_e)
    const float k0 = kp[k * 3 + 0], k1 = kp[k * 3 + 1], k2 = kp[k * 3 + 2];
    const float TWO_PI = 6.283185307179586f;
    for (int t = tid; t < m; t += nthr) {
        int e = elist[t] >> 1;
        float th = TWO_PI * (k0 * ecs[e * 3 + 0] + k1 * ecs[e * 3 + 1] + k2 * ecs[e * 3 + 2]);
        sins[t] = sinf(th);
    }
    __syncthreads();

    const int items = m * NFEAT;
    const int nr4 = NR >> 2;

    for (int d = 0; d < 3; ++d) {
        // zero the accumulator
        for (int x = tid; x < HR * MAXNR / 4; x += nthr)
            ((float4*)acc)[x] = make_float4(0.f, 0.f, 0.f, 0.f);
        __syncthreads();

        // scatter incident-edge contributions into owned rows (LDS atomics)
        for (int it = tid; it < items; it += nthr) {
            int t   = it / NFEAT;
            int f   = it - t * NFEAT;
            int ent = elist[t];
            int e   = ent >> 1;
            int dir = ent & 1;
            int row = dir ? g_oj[f] : g_oi[f];
            int rr  = row - r0;
            if ((unsigned)rr < HR) {
                int j   = dir ? eidx[e] : eidx[E + e];    // other endpoint
                int col = j * NO + (dir ? g_oi[f] : g_oj[f]);
                float val = -ev[e * 3 + d] * sins[t] * g_fac[f] * ef[e * NFEAT + f];
                atomicAdd(&acc[rr * MAXNR + col], val);
            }
        }
        // onsite diagonal block: D + D^T at block (i,i)
        for (int f = tid; f < NFEAT; f += nthr) {
            float v = g_fac[f] * nf[i * NFEAT + f];
            int ra = g_oi[f] - r0, ca = i * NO + g_oj[f];
            int rb = g_oj[f] - r0, cb = i * NO + g_oi[f];
            if ((unsigned)ra < HR) atomicAdd(&acc[ra * MAXNR + ca], v);
            if ((unsigned)rb < HR) atomicAdd(&acc[rb * MAXNR + cb], v);
        }
        __syncthreads();

        // stream owned rows to global, coalesced float4
        size_t base = ((size_t)(d * NK + k)) * NR * NR + (size_t)(i * NO + r0) * NR;
        if ((NR & 3) == 0) {
            for (int x = tid; x < HR * nr4; x += nthr) {
                int r  = x / nr4;
                int c4 = x - r * nr4;
                size_t idx = base + (size_t)r * NR + (size_t)c4 * 4;
                if (idx + 3 < lim) {
                    float4 v = *(float4*)&acc[r * MAXNR + c4 * 4];
                    *(float4*)(out + idx) = v;
                }
            }
        } else {
            for (int x = tid; x < HR * NR; x += nthr) {
                int r = x / NR, c = x - r * NR;
                size_t idx = base + (size_t)r * NR + c;
                if (idx < lim) out[idx] = acc[r * MAXNR + c];
            }
        }
        __syncthreads();
    }
}

extern "C" void kernel_launch(void* const* d_in, const int* in_sizes, int n_in,
                              void* d_out, int out_size, void* d_ws, size_t ws_size,
                              hipStream_t stream) {
    const float* ef  = (const float*)d_in[0];   // edge_features   [E,68]
    const float* nf  = (const float*)d_in[1];   // node_features   [N,68]
    const float* ev  = (const float*)d_in[2];   // edge_vectors    [E,3]
    const float* ecs = (const float*)d_in[3];   // edge_cell_shift [E,3]
    const float* kp  = (const float*)d_in[4];   // kpoints         [NK,3]
    const int*  eidx = (const int*)d_in[5];     // edge_index      [2,E]
    float* out = (float*)d_out;

    int E  = in_sizes[0] / NFEAT;
    int N  = in_sizes[1] / NFEAT;
    int NK = in_sizes[4] / 3;

    size_t lim = (size_t)out_size;   // confirmed: out_size = 3*NK*(N*NO)^2 floats (real part)

    dim3 grid(N, NK, NO / HR);       // (200, 4, 2) = 1600 workgroups
    fused_kernel<<<grid, 512, 0, stream>>>(ef, nf, ev, ecs, kp, eidx, out, E, N, NK, lim);
}